// Round 1
// baseline (69.643 us; speedup 1.0000x reference)
//
#include <hip/hip_runtime.h>

namespace {

constexpr int T   = 16384;
constexpr int B   = 8;
constexpr int C4  = 64;            // 256 fp32 channels as 64 float4
constexpr int SUB = 64;            // timesteps per wave
constexpr int WAVES_PER_BLOCK = 4; // block = 256 threads
constexpr int BLOCK_T = SUB * WAVES_PER_BLOCK; // 256 timesteps per block

template <bool GUARD>
__device__ __forceinline__ float4 ldx(const float4* __restrict__ xb, int tt) {
    if (GUARD) {
        if (tt < 0 || tt >= T) return float4{0.f, 0.f, 0.f, 0.f};
    }
    return xb[(size_t)tt * C4];
}

template <bool GUARD>
__device__ __forceinline__ void run_chunk(const float4* __restrict__ xb,
                                          float4* __restrict__ ob, int t0) {
    constexpr float INV = 1.0f / 11.0f;
    float4 s = {0.f, 0.f, 0.f, 0.f};
    // prologue: window for output t0 = sum over [t0-5, t0+5]
    #pragma unroll
    for (int k = -5; k <= 5; ++k) {
        float4 v = ldx<GUARD>(xb, t0 + k);
        s.x += v.x; s.y += v.y; s.z += v.z; s.w += v.w;
    }
    float4 o;
    o.x = s.x * INV; o.y = s.y * INV; o.z = s.z * INV; o.w = s.w * INV;
    ob[(size_t)t0 * C4] = o;
    // slide: window for t is [t-5, t+5]; add x[t+5], drop x[t-6]
    #pragma unroll 8
    for (int i = 1; i < SUB; ++i) {
        const int t = t0 + i;
        float4 a = ldx<GUARD>(xb, t + 5);
        float4 d = ldx<GUARD>(xb, t - 6);
        s.x += a.x - d.x; s.y += a.y - d.y; s.z += a.z - d.z; s.w += a.w - d.w;
        o.x = s.x * INV; o.y = s.y * INV; o.z = s.z * INV; o.w = s.w * INV;
        ob[(size_t)t * C4] = o;
    }
}

__global__ __launch_bounds__(256) void runavg_kernel(const float4* __restrict__ x,
                                                     float4* __restrict__ out) {
    const int lane = threadIdx.x & 63;   // channel-group (float4) index
    const int wid  = threadIdx.x >> 6;   // wave within block -> time sub-chunk
    const int chunks_per_batch = T / BLOCK_T;       // 64
    const int b  = blockIdx.x / chunks_per_batch;
    const int t0 = (blockIdx.x % chunks_per_batch) * BLOCK_T + wid * SUB;

    const float4* __restrict__ xb = x   + (size_t)b * T * C4 + lane;
    float4* __restrict__       ob = out + (size_t)b * T * C4 + lane;

    // fast path: every load in [t0-5, t0+SUB+4] is in-range
    if (t0 >= 5 && t0 + SUB + 5 <= T) {
        run_chunk<false>(xb, ob, t0);
    } else {
        run_chunk<true>(xb, ob, t0);
    }
}

} // namespace

extern "C" void kernel_launch(void* const* d_in, const int* in_sizes, int n_in,
                              void* d_out, int out_size, void* d_ws, size_t ws_size,
                              hipStream_t stream) {
    const float4* x = (const float4*)d_in[0];
    float4* out = (float4*)d_out;
    const int grid = B * (T / BLOCK_T);  // 512 blocks
    runavg_kernel<<<grid, 256, 0, stream>>>(x, out);
}

// Round 2
// 61.716 us; speedup vs baseline: 1.1284x; 1.1284x over previous
//
#include <hip/hip_runtime.h>

namespace {

constexpr int T   = 16384;
constexpr int B   = 8;
constexpr int C4  = 64;            // 256 fp32 channels as 64 float4
constexpr int SUB = 16;            // timesteps per wave (small -> more waves)
constexpr int WAVES_PER_BLOCK = 4; // block = 256 threads
constexpr int BLOCK_T = SUB * WAVES_PER_BLOCK; // 64 timesteps per block

template <bool GUARD>
__device__ __forceinline__ float4 ldx(const float4* __restrict__ xb, int tt) {
    if (GUARD) {
        if (tt < 0 || tt >= T) return float4{0.f, 0.f, 0.f, 0.f};
    }
    return xb[(size_t)tt * C4];
}

template <bool GUARD>
__device__ __forceinline__ void run_chunk(const float4* __restrict__ xb,
                                          float4* __restrict__ ob, int t0) {
    constexpr float INV = 1.0f / 11.0f;
    float4 s = {0.f, 0.f, 0.f, 0.f};
    // prologue: window for output t0 = sum over [t0-5, t0+5]
    #pragma unroll
    for (int k = -5; k <= 5; ++k) {
        float4 v = ldx<GUARD>(xb, t0 + k);
        s.x += v.x; s.y += v.y; s.z += v.z; s.w += v.w;
    }
    float4 o;
    o.x = s.x * INV; o.y = s.y * INV; o.z = s.z * INV; o.w = s.w * INV;
    ob[(size_t)t0 * C4] = o;
    // slide: window for t is [t-5, t+5]; add x[t+5], drop x[t-6]
    #pragma unroll
    for (int i = 1; i < SUB; ++i) {
        const int t = t0 + i;
        float4 a = ldx<GUARD>(xb, t + 5);
        float4 d = ldx<GUARD>(xb, t - 6);
        s.x += a.x - d.x; s.y += a.y - d.y; s.z += a.z - d.z; s.w += a.w - d.w;
        o.x = s.x * INV; o.y = s.y * INV; o.z = s.z * INV; o.w = s.w * INV;
        ob[(size_t)t * C4] = o;
    }
}

__global__ __launch_bounds__(256) void runavg_kernel(const float4* __restrict__ x,
                                                     float4* __restrict__ out) {
    const int lane = threadIdx.x & 63;   // channel-group (float4) index
    const int wid  = threadIdx.x >> 6;   // wave within block -> time sub-chunk
    const int chunks_per_batch = T / BLOCK_T;       // 256
    const int b  = blockIdx.x / chunks_per_batch;
    const int t0 = (blockIdx.x % chunks_per_batch) * BLOCK_T + wid * SUB;

    const float4* __restrict__ xb = x   + (size_t)b * T * C4 + lane;
    float4* __restrict__       ob = out + (size_t)b * T * C4 + lane;

    // fast path: every load in [t0-5, t0+SUB+4] is in-range
    if (t0 >= 5 && t0 + SUB + 5 <= T) {
        run_chunk<false>(xb, ob, t0);
    } else {
        run_chunk<true>(xb, ob, t0);
    }
}

} // namespace

extern "C" void kernel_launch(void* const* d_in, const int* in_sizes, int n_in,
                              void* d_out, int out_size, void* d_ws, size_t ws_size,
                              hipStream_t stream) {
    const float4* x = (const float4*)d_in[0];
    float4* out = (float4*)d_out;
    const int grid = B * (T / BLOCK_T);  // 2048 blocks
    runavg_kernel<<<grid, 256, 0, stream>>>(x, out);
}